// Round 5
// baseline (192.118 us; speedup 1.0000x reference)
//
#include <hip/hip_runtime.h>
#include <math.h>

#define NB 2
#define NO 512
#define NQ 512
#define LATENT 256
#define NHEADS 8
#define HEAD_DIM 32
#define HD 256
#define OUT_DIM 128
#define LPAD 520   // logits row pitch (floats): float4-aligned, spreads banks

typedef __attribute__((ext_vector_type(8))) short short8;   // 8 bf16 (4 VGPRs)
typedef __attribute__((ext_vector_type(4))) float f32x4;    // MFMA accumulator

__device__ __forceinline__ float softplus_f(float x) {
  return x > 0.0f ? x + log1pf(expf(-x)) : log1pf(expf(x));
}

// round-to-nearest-even fp32 -> bf16 bits
__device__ __forceinline__ unsigned short bf16_rne(float f) {
  unsigned u = __float_as_uint(f);
  unsigned r = u + 0x7FFFu + ((u >> 16) & 1u);
  return (unsigned short)(r >> 16);
}
__device__ __forceinline__ float bf16_to_f32(unsigned short h) {
  return __uint_as_float(((unsigned)h) << 16);
}

// ---------------------------------------------------------------------------
// Prep kernel, one dispatch, 512 blocks x 1024 threads.
// Blocks 0..255: fused 2-layer feature MLP (hidden stays in LDS) -> V.
// Blocks 256..511: AO[b][o][j] = sum_i pos_obs[b][o][i]*(kw1[3+i][j]-kw1[6+i][j]).
__global__ __launch_bounds__(1024) void prep_kernel(
    const float* __restrict__ h_obs, const float* __restrict__ fw1,
    const float* __restrict__ fb1, const float* __restrict__ fw2,
    const float* __restrict__ fb2, const float* __restrict__ pos_obs,
    const float* __restrict__ kw1, float* __restrict__ V,
    float* __restrict__ AO)
{
  if (blockIdx.x < 256) {
    __shared__ float s_red[4][4][256];
    __shared__ float s_hid[4][256];
    const int n  = threadIdx.x & 255;
    const int ks = threadIdx.x >> 8;
    const int r0 = blockIdx.x * 4;
    const int k0 = ks * 64;
    // layer 1 (k-split 4)
    float a0 = 0.f, a1 = 0.f, a2 = 0.f, a3 = 0.f;
    #pragma unroll 8
    for (int kk = 0; kk < 64; ++kk) {
      int k = k0 + kk;
      float w = fw1[k * 256 + n];
      a0 = fmaf(h_obs[(r0 + 0) * 256 + k], w, a0);
      a1 = fmaf(h_obs[(r0 + 1) * 256 + k], w, a1);
      a2 = fmaf(h_obs[(r0 + 2) * 256 + k], w, a2);
      a3 = fmaf(h_obs[(r0 + 3) * 256 + k], w, a3);
    }
    s_red[ks][0][n] = a0; s_red[ks][1][n] = a1;
    s_red[ks][2][n] = a2; s_red[ks][3][n] = a3;
    __syncthreads();
    if (ks == 0) {
      float bb = fb1[n];
      #pragma unroll
      for (int r = 0; r < 4; ++r) {
        float v = s_red[0][r][n] + s_red[1][r][n] + s_red[2][r][n] + s_red[3][r][n] + bb;
        s_hid[r][n] = fmaxf(v, 0.f);
      }
    }
    __syncthreads();
    // layer 2 (k-split 4), hidden from LDS (broadcast reads)
    float c0 = 0.f, c1 = 0.f, c2 = 0.f, c3 = 0.f;
    #pragma unroll 8
    for (int kk = 0; kk < 64; ++kk) {
      int k = k0 + kk;
      float w = fw2[k * 256 + n];
      c0 = fmaf(s_hid[0][k], w, c0);
      c1 = fmaf(s_hid[1][k], w, c1);
      c2 = fmaf(s_hid[2][k], w, c2);
      c3 = fmaf(s_hid[3][k], w, c3);
    }
    __syncthreads();
    s_red[ks][0][n] = c0; s_red[ks][1][n] = c1;
    s_red[ks][2][n] = c2; s_red[ks][3][n] = c3;
    __syncthreads();
    if (ks == 0) {
      float bb = fb2[n];
      #pragma unroll
      for (int r = 0; r < 4; ++r) {
        float v = s_red[0][r][n] + s_red[1][r][n] + s_red[2][r][n] + s_red[3][r][n] + bb;
        V[(r0 + r) * 256 + n] = v;
      }
    }
  } else {
    const int i  = blockIdx.x - 256;
    const int b  = i >> 7;
    const int og = i & 127;
    const int ol = threadIdx.x >> 8;
    const int j  = threadIdx.x & 255;
    const int o  = og * 4 + ol;
    float c0 = kw1[3 * 256 + j] - kw1[6 * 256 + j];
    float c1 = kw1[4 * 256 + j] - kw1[7 * 256 + j];
    float c2 = kw1[5 * 256 + j] - kw1[8 * 256 + j];
    const float* p = pos_obs + ((size_t)(b * NO + o)) * 3;
    AO[(size_t)(b * NO + o) * 256 + j] = fmaf(p[0], c0, fmaf(p[1], c1, p[2] * c2));
  }
}

// ---------------------------------------------------------------------------
// Fused attention + out_proj. QT=2 queries/block, 512 threads (8 waves).
// Phase 1 uses mfma_f32_16x16x32_bf16 with split-bf16 (hi+lo, 3 products)
// for near-fp32 accuracy: delta[o,h] = sum_j relu(aq[j]+ao[o,j]) * kw2[j,h].
__global__ __launch_bounds__(512, 4) void attn_fused(
    const float* __restrict__ V,         // (B*NO, 256)
    const float* __restrict__ AO,        // (B*NO, 256)
    const float* __restrict__ kw1,       // (9, 256)
    const float* __restrict__ kb1,       // (256)
    const float* __restrict__ kw2,       // (256, 8)
    const float* __restrict__ kb2,       // (8)
    const float* __restrict__ log_sigma, // (8)
    const float* __restrict__ pos_obs,   // (B*NO, 3)
    const float* __restrict__ pos_query, // (B*NQ, 3)
    const float* __restrict__ ow,        // (256, 128)
    const float* __restrict__ obias,     // (128)
    const float* __restrict__ vw,        // (256, 128)
    const float* __restrict__ vbias,     // (128)
    float* __restrict__ out)             // mean | var_out
{
  __shared__ float s_logits[2][8 * LPAD];          // 33,280 B
  __shared__ __align__(16) char poolA[16384];      // B-frags | s_red[512][8]
  __shared__ __align__(16) char poolB[8192];       // aq[2][256]+d2[2][512] | s_hv
  __shared__ float s_sum[2][8];
  __shared__ float s_invs2[8];
  __shared__ float s_kb2v[8];

  short8* Bhi = (short8*)poolA;                    // [kstep*64 + lane]
  short8* Blo = (short8*)(poolA + 8192);
  float*  s_aq = (float*)poolB;                    // [q*256 + j]
  float*  s_d2 = (float*)(poolB + 2048);           // [q*512 + o]

  const int t   = threadIdx.x;
  const int bq0 = blockIdx.x * 2;
  const int b   = bq0 >> 9;

  // ---- prologue -----------------------------------------------------------
  // query positions (block-uniform)
  float pqx[2], pqy[2], pqz[2];
  #pragma unroll
  for (int q = 0; q < 2; ++q) {
    pqx[q] = pos_query[(bq0 + q) * 3 + 0];
    pqy[q] = pos_query[(bq0 + q) * 3 + 1];
    pqz[q] = pos_query[(bq0 + q) * 3 + 2];
  }
  // aq[q][j], thread t -> (q = t>>8, j = t&255)
  {
    const int q = t >> 8, j = t & 255;
    float c0 = kw1[0 * 256 + j] + kw1[6 * 256 + j];
    float c1 = kw1[1 * 256 + j] + kw1[7 * 256 + j];
    float c2 = kw1[2 * 256 + j] + kw1[8 * 256 + j];
    s_aq[q * 256 + j] =
        fmaf(pqx[q], c0, fmaf(pqy[q], c1, fmaf(pqz[q], c2, kb1[j])));
  }
  // d2[q][o], thread t -> o = t
  {
    const int o = t;
    const float* p = pos_obs + (size_t)(b * NO + o) * 3;
    float px = p[0], py = p[1], pz = p[2];
    #pragma unroll
    for (int q = 0; q < 2; ++q) {
      float r0 = pqx[q] - px, r1 = pqy[q] - py, r2 = pqz[q] - pz;
      s_d2[q * 512 + o] = r0 * r0 + r1 * r1 + r2 * r2;
    }
  }
  // B-fragments (split bf16): thread t -> (kstep = t>>6, lane = t&63)
  {
    const int kstep = t >> 6, lane = t & 63;
    const int nh = lane & 15;
    const int kb_ = kstep * 32 + ((lane >> 4) & 3) * 8;
    short8 hi8, lo8;
    #pragma unroll
    for (int i = 0; i < 8; ++i) {
      float v = (nh < 8) ? kw2[(kb_ + i) * 8 + nh] : 0.f;
      unsigned short h = bf16_rne(v);
      hi8[i] = (short)h;
      lo8[i] = (short)bf16_rne(v - bf16_to_f32(h));
    }
    Bhi[kstep * 64 + lane] = hi8;
    Blo[kstep * 64 + lane] = lo8;
  }
  if (t < 8) {
    float s = expf(log_sigma[t]);
    s_invs2[t] = 1.0f / (s * s + 1e-6f);
    s_kb2v[t]  = kb2[t];
  }
  __syncthreads();

  // ---- phase 1: MFMA delta + logits --------------------------------------
  {
    const int wave = t >> 6, lane = t & 63;
    const int q    = wave >> 2;
    const int quad = lane >> 4, mrow = lane & 15;
    const int otb  = (wave & 3) * 8;          // this wave's 8 o-tiles
    f32x4 C[8];
    #pragma unroll
    for (int jt = 0; jt < 8; ++jt) C[jt] = (f32x4){0.f, 0.f, 0.f, 0.f};

    const float* aqq = s_aq + q * 256;
    for (int kstep = 0; kstep < 8; ++kstep) {
      const int koff = kstep * 32 + quad * 8;
      float4 aqA = *(const float4*)(aqq + koff);
      float4 aqB = *(const float4*)(aqq + koff + 4);
      short8 bhi = Bhi[kstep * 64 + lane];
      short8 blo = Blo[kstep * 64 + lane];
      #pragma unroll 2
      for (int jt = 0; jt < 8; ++jt) {
        const int o = (otb + jt) * 16 + mrow;
        const float* aop = AO + ((size_t)(b * NO + o) * 256 + koff);
        float4 aoA = *(const float4*)aop;
        float4 aoB = *(const float4*)(aop + 4);
        float hv[8];
        hv[0] = fmaxf(aqA.x + aoA.x, 0.f);
        hv[1] = fmaxf(aqA.y + aoA.y, 0.f);
        hv[2] = fmaxf(aqA.z + aoA.z, 0.f);
        hv[3] = fmaxf(aqA.w + aoA.w, 0.f);
        hv[4] = fmaxf(aqB.x + aoB.x, 0.f);
        hv[5] = fmaxf(aqB.y + aoB.y, 0.f);
        hv[6] = fmaxf(aqB.z + aoB.z, 0.f);
        hv[7] = fmaxf(aqB.w + aoB.w, 0.f);
        short8 ahi, alo;
        #pragma unroll
        for (int i = 0; i < 8; ++i) {
          unsigned short h = bf16_rne(hv[i]);
          ahi[i] = (short)h;
          alo[i] = (short)bf16_rne(hv[i] - bf16_to_f32(h));
        }
        C[jt] = __builtin_amdgcn_mfma_f32_16x16x32_bf16(alo, bhi, C[jt], 0, 0, 0);
        C[jt] = __builtin_amdgcn_mfma_f32_16x16x32_bf16(ahi, blo, C[jt], 0, 0, 0);
        C[jt] = __builtin_amdgcn_mfma_f32_16x16x32_bf16(ahi, bhi, C[jt], 0, 0, 0);
      }
    }
    // logits epilogue: lane holds D[n=h=lane&15][m-rows quad*4+r]
    const int h = lane & 15;
    if (h < 8) {
      const float inv = s_invs2[h];
      const float kbv = s_kb2v[h];
      #pragma unroll
      for (int jt = 0; jt < 8; ++jt) {
        const int ob = (otb + jt) * 16 + quad * 4;
        #pragma unroll
        for (int r = 0; r < 4; ++r) {
          const int o = ob + r;
          float lg = logf(expf(-s_d2[q * 512 + o] * inv) + 1e-8f) + C[jt][r] + kbv;
          s_logits[q][h * LPAD + o] = lg;
        }
      }
    }
  }
  __syncthreads();

  // ---- phase 2: softmax (8 waves x 2 (q,h) combos) ------------------------
  {
    const int wave = t >> 6, lane = t & 63;
    #pragma unroll
    for (int cc = 0; cc < 2; ++cc) {
      const int c = wave * 2 + cc;          // 0..15
      const int q = c >> 3, h = c & 7;
      float* pl = &s_logits[q][h * LPAD];
      float l[8];
      float m = -1e30f;
      #pragma unroll
      for (int k = 0; k < 8; ++k) {
        l[k] = pl[k * 64 + lane];
        m = fmaxf(m, l[k]);
      }
      #pragma unroll
      for (int off = 32; off >= 1; off >>= 1) m = fmaxf(m, __shfl_xor(m, off, 64));
      float s = 0.f;
      #pragma unroll
      for (int k = 0; k < 8; ++k) {
        float p = expf(l[k] - m);
        pl[k * 64 + lane] = p;
        s += p;
      }
      #pragma unroll
      for (int off = 32; off >= 1; off >>= 1) s += __shfl_xor(s, off, 64);
      if (lane == 0) s_sum[q][h] = s;
    }
  }
  __syncthreads();

  // ---- phase 3: weighted mean / E[v^2] (s_red overlays B-frags) -----------
  float (*s_red)[8] = (float(*)[8])poolA;
  {
    const int q  = t >> 8;
    const int qt = (t >> 6) & 3;            // o-quarter
    const int hd = t & 63;
    const int h  = hd >> 3;
    const int dg = hd & 7;
    const float* vbase = V + (size_t)b * NO * 256 + (size_t)(qt * 128) * 256
                           + h * 32 + dg * 4;
    const float* pl = &s_logits[q][h * LPAD + qt * 128];
    float s1x = 0.f, s1y = 0.f, s1z = 0.f, s1w = 0.f;
    float s2x = 0.f, s2y = 0.f, s2z = 0.f, s2w = 0.f;
    #pragma unroll 2
    for (int oi = 0; oi < 128; oi += 4) {
      float4 pv = *(const float4*)&pl[oi];
      #pragma unroll
      for (int i = 0; i < 4; ++i) {
        float p = (&pv.x)[i];
        float4 vv = *(const float4*)(vbase + (size_t)(oi + i) * 256);
        s1x = fmaf(p, vv.x, s1x); s2x = fmaf(p * vv.x, vv.x, s2x);
        s1y = fmaf(p, vv.y, s1y); s2y = fmaf(p * vv.y, vv.y, s2y);
        s1z = fmaf(p, vv.z, s1z); s2z = fmaf(p * vv.z, vv.z, s2z);
        s1w = fmaf(p, vv.w, s1w); s2w = fmaf(p * vv.w, vv.w, s2w);
      }
    }
    s_red[t][0] = s1x; s_red[t][1] = s1y; s_red[t][2] = s1z; s_red[t][3] = s1w;
    s_red[t][4] = s2x; s_red[t][5] = s2y; s_red[t][6] = s2z; s_red[t][7] = s2w;
  }
  __syncthreads();

  // ---- reduce quarters -> s_hv (overlays aq/d2) ---------------------------
  float* s_hv = (float*)poolB;              // [q][mode][256]
  {
    const int q  = t >> 8;
    const int hd = t & 255;
    const int h  = hd >> 5, d = hd & 31, dg = d >> 2, c = d & 3;
    const int rb = q * 256 + h * 8 + dg;
    float S1 = 0.f, S2 = 0.f;
    #pragma unroll
    for (int qi = 0; qi < 4; ++qi) {
      S1 += s_red[rb + qi * 64][c];
      S2 += s_red[rb + qi * 64][4 + c];
    }
    float inv = 1.0f / s_sum[q][h];
    float m1 = S1 * inv;
    float va = fmaxf(S2 * inv - m1 * m1, 0.f);
    s_hv[(q * 2 + 0) * 256 + hd] = m1;
    s_hv[(q * 2 + 1) * 256 + hd] = va;
  }
  __syncthreads();

  // ---- phase 4: fused output projection -----------------------------------
  {
    const int q    = t >> 8;
    const int mode = (t >> 7) & 1;
    const int n    = t & 127;
    const float* W  = mode ? vw : ow;
    const float  bb = mode ? vbias[n] : obias[n];
    const float* X  = s_hv + (q * 2 + mode) * 256;
    float acc = bb;
    #pragma unroll 4
    for (int k = 0; k < 256; k += 4) {
      float4 x = *(const float4*)&X[k];
      acc = fmaf(x.x, W[(k + 0) * 128 + n], acc);
      acc = fmaf(x.y, W[(k + 1) * 128 + n], acc);
      acc = fmaf(x.z, W[(k + 2) * 128 + n], acc);
      acc = fmaf(x.w, W[(k + 3) * 128 + n], acc);
    }
    if (mode) acc = softplus_f(acc);
    float* dst = out + (size_t)mode * (NB * NQ * OUT_DIM);
    dst[(size_t)(bq0 + q) * OUT_DIM + n] = acc;
  }
}

// ---------------------------------------------------------------------------
extern "C" void kernel_launch(void* const* d_in, const int* in_sizes, int n_in,
                              void* d_out, int out_size, void* d_ws, size_t ws_size,
                              hipStream_t stream)
{
  const float* h_obs     = (const float*)d_in[0];
  const float* pos_obs   = (const float*)d_in[1];
  const float* pos_query = (const float*)d_in[2];
  const float* fw1       = (const float*)d_in[3];
  const float* fb1       = (const float*)d_in[4];
  const float* fw2       = (const float*)d_in[5];
  const float* fb2       = (const float*)d_in[6];
  const float* log_sigma = (const float*)d_in[7];
  const float* kw1       = (const float*)d_in[8];
  const float* kb1       = (const float*)d_in[9];
  const float* kw2       = (const float*)d_in[10];
  const float* kb2       = (const float*)d_in[11];
  const float* ow        = (const float*)d_in[12];
  const float* ob        = (const float*)d_in[13];
  const float* vw        = (const float*)d_in[14];
  const float* vb        = (const float*)d_in[15];

  float* out = (float*)d_out;
  float* ws  = (float*)d_ws;

  float* V  = ws;                  // (B*NO, 256) = 262,144 floats
  float* AO = ws + 262144;         // (B*NO, 256) = 524,288 floats total offset

  prep_kernel<<<512, 1024, 0, stream>>>(h_obs, fw1, fb1, fw2, fb2,
                                        pos_obs, kw1, V, AO);
  attn_fused<<<NB * NQ / 2, 512, 0, stream>>>(V, AO, kw1, kb1, kw2, kb2,
                                              log_sigma, pos_obs, pos_query,
                                              ow, ob, vw, vb, out);
}

// Round 7
// 148.615 us; speedup vs baseline: 1.2927x; 1.2927x over previous
//
#include <hip/hip_runtime.h>
#include <math.h>

#define NB 2
#define NO 512
#define NQ 512
#define OUT_DIM 128
#define LPAD 520   // logits row pitch (floats)

typedef __attribute__((ext_vector_type(8))) short short8;   // 8 bf16
typedef __attribute__((ext_vector_type(4))) float f32x4;    // MFMA acc
typedef float v2f __attribute__((ext_vector_type(2)));

__device__ __forceinline__ float softplus_f(float x) {
  return x > 0.0f ? x + log1pf(expf(-x)) : log1pf(expf(x));
}
__device__ __forceinline__ unsigned short bf16_rne(float f) {
  unsigned u = __float_as_uint(f);
  unsigned r = u + 0x7FFFu + ((u >> 16) & 1u);
  return (unsigned short)(r >> 16);
}
__device__ __forceinline__ float bf16_to_f32(unsigned short h) {
  return __uint_as_float(((unsigned)h) << 16);
}
// pack 2 fp32 -> 2 bf16 (RNE) in one u32 (x = low half); manual bit path
__device__ __forceinline__ unsigned pack_bf2(float x, float y) {
  unsigned ux = __float_as_uint(x);
  unsigned uy = __float_as_uint(y);
  ux = ux + 0x7FFFu + ((ux >> 16) & 1u);
  uy = uy + 0x7FFFu + ((uy >> 16) & 1u);
  return (ux >> 16) | (uy & 0xFFFF0000u);
}
// unpack u32 (2 bf16) -> v2f {low, high}
__device__ __forceinline__ v2f unpk_bf2(unsigned u) {
  v2f r; r.x = __uint_as_float(u << 16); r.y = __uint_as_float(u & 0xFFFF0000u);
  return r;
}
__device__ __forceinline__ v2f splat2(float x) { v2f r; r.x = x; r.y = x; return r; }
__device__ __forceinline__ v2f fma2(v2f a, v2f b, v2f c) { return __builtin_elementwise_fma(a, b, c); }
__device__ __forceinline__ v2f max2(v2f a, v2f b) { return __builtin_elementwise_max(a, b); }

// ---------------------------------------------------------------------------
// Prep: blocks 0..255 fused 2-layer MLP -> V (bf16); 256..511 AO (bf16).
__global__ __launch_bounds__(1024) void prep_kernel(
    const float* __restrict__ h_obs, const float* __restrict__ fw1,
    const float* __restrict__ fb1, const float* __restrict__ fw2,
    const float* __restrict__ fb2, const float* __restrict__ pos_obs,
    const float* __restrict__ kw1, unsigned short* __restrict__ V_bf,
    unsigned short* __restrict__ AO_bf)
{
  if (blockIdx.x < 256) {
    __shared__ float s_red[4][4][256];
    __shared__ float s_hid[4][256];
    const int n  = threadIdx.x & 255;
    const int ks = threadIdx.x >> 8;
    const int r0 = blockIdx.x * 4;
    const int k0 = ks * 64;
    float a0 = 0.f, a1 = 0.f, a2 = 0.f, a3 = 0.f;
    #pragma unroll 8
    for (int kk = 0; kk < 64; ++kk) {
      int k = k0 + kk;
      float w = fw1[k * 256 + n];
      a0 = fmaf(h_obs[(r0 + 0) * 256 + k], w, a0);
      a1 = fmaf(h_obs[(r0 + 1) * 256 + k], w, a1);
      a2 = fmaf(h_obs[(r0 + 2) * 256 + k], w, a2);
      a3 = fmaf(h_obs[(r0 + 3) * 256 + k], w, a3);
    }
    s_red[ks][0][n] = a0; s_red[ks][1][n] = a1;
    s_red[ks][2][n] = a2; s_red[ks][3][n] = a3;
    __syncthreads();
    if (ks == 0) {
      float bb = fb1[n];
      #pragma unroll
      for (int r = 0; r < 4; ++r) {
        float v = s_red[0][r][n] + s_red[1][r][n] + s_red[2][r][n] + s_red[3][r][n] + bb;
        s_hid[r][n] = fmaxf(v, 0.f);
      }
    }
    __syncthreads();
    float c0 = 0.f, c1 = 0.f, c2 = 0.f, c3 = 0.f;
    #pragma unroll 8
    for (int kk = 0; kk < 64; ++kk) {
      int k = k0 + kk;
      float w = fw2[k * 256 + n];
      c0 = fmaf(s_hid[0][k], w, c0);
      c1 = fmaf(s_hid[1][k], w, c1);
      c2 = fmaf(s_hid[2][k], w, c2);
      c3 = fmaf(s_hid[3][k], w, c3);
    }
    __syncthreads();
    s_red[ks][0][n] = c0; s_red[ks][1][n] = c1;
    s_red[ks][2][n] = c2; s_red[ks][3][n] = c3;
    __syncthreads();
    if (ks == 0) {
      float bb = fb2[n];
      #pragma unroll
      for (int r = 0; r < 4; ++r) {
        float v = s_red[0][r][n] + s_red[1][r][n] + s_red[2][r][n] + s_red[3][r][n] + bb;
        V_bf[(size_t)(r0 + r) * 256 + n] = bf16_rne(v);
      }
    }
  } else {
    const int i  = blockIdx.x - 256;
    const int b  = i >> 7;
    const int og = i & 127;
    const int ol = threadIdx.x >> 8;
    const int j  = threadIdx.x & 255;
    const int o  = og * 4 + ol;
    float c0 = kw1[3 * 256 + j] - kw1[6 * 256 + j];
    float c1 = kw1[4 * 256 + j] - kw1[7 * 256 + j];
    float c2 = kw1[5 * 256 + j] - kw1[8 * 256 + j];
    const float* p = pos_obs + ((size_t)(b * NO + o)) * 3;
    AO_bf[(size_t)(b * NO + o) * 256 + j] =
        bf16_rne(fmaf(p[0], c0, fmaf(p[1], c1, p[2] * c2)));
  }
}

// ---------------------------------------------------------------------------
// Fused attention + out_proj. QT=2 per block, 512 threads (8 waves).
// Phase 1: MFMA 16x16x32_bf16; A = relu(aq+ao) single-bf16 (packed cvt),
//          B = kw2 split hi/lo bf16 (2 MFMAs). Each wave: 4 o-tiles x 2 q
//          (AO loaded ONCE, shared across q). Logits prefilled with rbf part.
__global__ __launch_bounds__(512, 4) void attn_fused(
    const unsigned short* __restrict__ V_bf,   // (B*NO, 256) bf16
    const unsigned short* __restrict__ AO_bf,  // (B*NO, 256) bf16
    const float* __restrict__ kw1,       // (9, 256)
    const float* __restrict__ kb1,       // (256)
    const float* __restrict__ kw2,       // (256, 8)
    const float* __restrict__ kb2,       // (8)
    const float* __restrict__ log_sigma, // (8)
    const float* __restrict__ pos_obs,   // (B*NO, 3)
    const float* __restrict__ pos_query, // (B*NQ, 3)
    const float* __restrict__ ow, const float* __restrict__ obias,
    const float* __restrict__ vw, const float* __restrict__ vbias,
    float* __restrict__ out)
{
  __shared__ float s_logits[2][8 * LPAD];        // 33,280 B
  __shared__ __align__(16) char poolA[18432];    // Bfrags 16K | s_red 18K | s_pred 4K
  __shared__ __align__(16) char poolB[4096];     // aq 2K | s_hv 4K
  __shared__ float s_sum[2][8];

  short8* Bhi    = (short8*)poolA;               // [kstep*64 + lane]
  short8* Blo    = (short8*)(poolA + 8192);
  float*  s_redA = (float*)poolA;                // [512][9]
  float*  s_pred = (float*)poolA;                // [ks][mode][q][128]
  float*  s_aq   = (float*)poolB;                // [q*256 + j]
  float*  s_hv   = (float*)poolB;                // [(q*2+mode)*256 + hd]

  const int t   = threadIdx.x;
  const int bq0 = blockIdx.x * 2;
  const int b   = bq0 >> 9;

  // ---- prologue -----------------------------------------------------------
  float pqx[2], pqy[2], pqz[2];
  #pragma unroll
  for (int q = 0; q < 2; ++q) {
    pqx[q] = pos_query[(bq0 + q) * 3 + 0];
    pqy[q] = pos_query[(bq0 + q) * 3 + 1];
    pqz[q] = pos_query[(bq0 + q) * 3 + 2];
  }
  // aq[q][j]
  {
    const int q = t >> 8, j = t & 255;
    float c0 = kw1[0 * 256 + j] + kw1[6 * 256 + j];
    float c1 = kw1[1 * 256 + j] + kw1[7 * 256 + j];
    float c2 = kw1[2 * 256 + j] + kw1[8 * 256 + j];
    s_aq[q * 256 + j] =
        fmaf(pqx[q], c0, fmaf(pqy[q], c1, fmaf(pqz[q], c2, kb1[j])));
  }
  // logits prefill: rbf + kb2 for o = t, both q, all h
  {
    const int o = t;
    const float* p = pos_obs + (size_t)(b * NO + o) * 3;
    float px = p[0], py = p[1], pz = p[2];
    float d2q[2];
    #pragma unroll
    for (int q = 0; q < 2; ++q) {
      float r0 = pqx[q] - px, r1 = pqy[q] - py, r2 = pqz[q] - pz;
      d2q[q] = r0 * r0 + r1 * r1 + r2 * r2;
    }
    #pragma unroll
    for (int h = 0; h < 8; ++h) {
      float sg  = expf(log_sigma[h]);
      float inv = 1.0f / (sg * sg + 1e-6f);
      float kbv = kb2[h];
      s_logits[0][h * LPAD + o] = logf(expf(-d2q[0] * inv) + 1e-8f) + kbv;
      s_logits[1][h * LPAD + o] = logf(expf(-d2q[1] * inv) + 1e-8f) + kbv;
    }
  }
  // B fragments: kw2 split bf16 hi/lo
  {
    const int kstep = t >> 6, lane = t & 63;
    const int nh = lane & 15;
    const int kb_ = kstep * 32 + ((lane >> 4) & 3) * 8;
    short8 hi8, lo8;
    #pragma unroll
    for (int i = 0; i < 8; ++i) {
      float v = (nh < 8) ? kw2[(kb_ + i) * 8 + nh] : 0.f;
      unsigned short h = bf16_rne(v);
      hi8[i] = (short)h;
      lo8[i] = (short)bf16_rne(v - bf16_to_f32(h));
    }
    Bhi[kstep * 64 + lane] = hi8;
    Blo[kstep * 64 + lane] = lo8;
  }
  __syncthreads();

  // ---- phase 1: MFMA delta, accumulate into prefetched logits -------------
  {
    const int wave = t >> 6, lane = t & 63;
    const int quad = lane >> 4, mrow = lane & 15;
    const int tb   = wave * 4;                   // 4 o-tiles per wave, both q
    f32x4 C[2][4];
    #pragma unroll
    for (int q = 0; q < 2; ++q)
      #pragma unroll
      for (int jt = 0; jt < 4; ++jt) C[q][jt] = (f32x4){0.f, 0.f, 0.f, 0.f};

    for (int kstep = 0; kstep < 8; ++kstep) {
      const int koff = kstep * 32 + quad * 8;
      const v2f* aqp0 = (const v2f*)(s_aq + koff);
      const v2f* aqp1 = (const v2f*)(s_aq + 256 + koff);
      v2f aq0[4], aq1[4];
      #pragma unroll
      for (int i = 0; i < 4; ++i) { aq0[i] = aqp0[i]; aq1[i] = aqp1[i]; }
      short8 bhi = Bhi[kstep * 64 + lane];
      short8 blo = Blo[kstep * 64 + lane];
      #pragma unroll
      for (int jt = 0; jt < 4; ++jt) {
        const int o = (tb + jt) * 16 + mrow;
        int4 u = *(const int4*)(AO_bf + ((size_t)(b * NO + o) << 8) + koff);
        v2f ao[4];
        ao[0] = unpk_bf2((unsigned)u.x); ao[1] = unpk_bf2((unsigned)u.y);
        ao[2] = unpk_bf2((unsigned)u.z); ao[3] = unpk_bf2((unsigned)u.w);
        v2f z = splat2(0.f);
        int4 af0, af1;
        {
          v2f h0 = max2(aq0[0] + ao[0], z), h1 = max2(aq0[1] + ao[1], z);
          v2f h2 = max2(aq0[2] + ao[2], z), h3 = max2(aq0[3] + ao[3], z);
          af0.x = (int)pack_bf2(h0.x, h0.y); af0.y = (int)pack_bf2(h1.x, h1.y);
          af0.z = (int)pack_bf2(h2.x, h2.y); af0.w = (int)pack_bf2(h3.x, h3.y);
        }
        {
          v2f h0 = max2(aq1[0] + ao[0], z), h1 = max2(aq1[1] + ao[1], z);
          v2f h2 = max2(aq1[2] + ao[2], z), h3 = max2(aq1[3] + ao[3], z);
          af1.x = (int)pack_bf2(h0.x, h0.y); af1.y = (int)pack_bf2(h1.x, h1.y);
          af1.z = (int)pack_bf2(h2.x, h2.y); af1.w = (int)pack_bf2(h3.x, h3.y);
        }
        short8 a0 = __builtin_bit_cast(short8, af0);
        short8 a1 = __builtin_bit_cast(short8, af1);
        C[0][jt] = __builtin_amdgcn_mfma_f32_16x16x32_bf16(a0, bhi, C[0][jt], 0, 0, 0);
        C[0][jt] = __builtin_amdgcn_mfma_f32_16x16x32_bf16(a0, blo, C[0][jt], 0, 0, 0);
        C[1][jt] = __builtin_amdgcn_mfma_f32_16x16x32_bf16(a1, bhi, C[1][jt], 0, 0, 0);
        C[1][jt] = __builtin_amdgcn_mfma_f32_16x16x32_bf16(a1, blo, C[1][jt], 0, 0, 0);
      }
    }
    // epilogue: D[n=h=lane&15][m=quad*4+r]; add delta into prefilled logits
    const int h = lane & 15;
    if (h < 8) {
      #pragma unroll
      for (int q = 0; q < 2; ++q)
        #pragma unroll
        for (int jt = 0; jt < 4; ++jt) {
          const int ob = (tb + jt) * 16 + quad * 4;
          #pragma unroll
          for (int r = 0; r < 4; ++r)
            s_logits[q][h * LPAD + ob + r] += C[q][jt][r];
        }
    }
  }
  __syncthreads();

  // ---- phase 2: softmax (8 waves x 2 (q,h) rows) --------------------------
  {
    const int wave = t >> 6, lane = t & 63;
    #pragma unroll
    for (int cc = 0; cc < 2; ++cc) {
      const int c = wave * 2 + cc;
      const int q = c >> 3, h = c & 7;
      float* pl = &s_logits[q][h * LPAD];
      float l[8];
      float m = -1e30f;
      #pragma unroll
      for (int k = 0; k < 8; ++k) {
        l[k] = pl[k * 64 + lane];
        m = fmaxf(m, l[k]);
      }
      #pragma unroll
      for (int off = 32; off >= 1; off >>= 1) m = fmaxf(m, __shfl_xor(m, off, 64));
      float s = 0.f;
      #pragma unroll
      for (int k = 0; k < 8; ++k) {
        float p = expf(l[k] - m);
        pl[k * 64 + lane] = p;
        s += p;
      }
      #pragma unroll
      for (int off = 32; off >= 1; off >>= 1) s += __shfl_xor(s, off, 64);
      if (lane == 0) s_sum[q][h] = s;
    }
  }
  __syncthreads();

  // ---- phase 3: PV + P V^2, V loaded once, both q per thread --------------
  float q1p[8];
  {
    const int s  = t >> 6;                 // o-slice of 64
    const int r  = t & 63;
    const int h  = r >> 3, dg = r & 7;
    const unsigned short* vb_ = V_bf + ((size_t)(b * NO) << 8) + h * 32 + dg * 4;
    const float* P0 = &s_logits[0][h * LPAD];
    const float* P1 = &s_logits[1][h * LPAD];
    v2f s1a0 = splat2(0.f), s1b0 = splat2(0.f), s2a0 = splat2(0.f), s2b0 = splat2(0.f);
    v2f s1a1 = splat2(0.f), s1b1 = splat2(0.f), s2a1 = splat2(0.f), s2b1 = splat2(0.f);
    const int o0 = s * 64;
    #pragma unroll 4
    for (int oi = 0; oi < 64; ++oi) {
      const int o = o0 + oi;
      uint2 vv = *(const uint2*)(vb_ + ((size_t)o << 8));
      v2f va  = unpk_bf2(vv.x);
      v2f vb2 = unpk_bf2(vv.y);
      v2f p0 = splat2(P0[o]), p1 = splat2(P1[o]);
      s1a0 = fma2(p0, va, s1a0);  s1b0 = fma2(p0, vb2, s1b0);
      v2f t0a = p0 * va, t0b = p0 * vb2;
      s2a0 = fma2(t0a, va, s2a0); s2b0 = fma2(t0b, vb2, s2b0);
      s1a1 = fma2(p1, va, s1a1);  s1b1 = fma2(p1, vb2, s1b1);
      v2f t1a = p1 * va, t1b = p1 * vb2;
      s2a1 = fma2(t1a, va, s2a1); s2b1 = fma2(t1b, vb2, s2b1);
    }
    float* row = s_redA + t * 9;
    row[0] = s1a0.x; row[1] = s1a0.y; row[2] = s1b0.x; row[3] = s1b0.y;
    row[4] = s2a0.x; row[5] = s2a0.y; row[6] = s2b0.x; row[7] = s2b0.y;
    q1p[0] = s1a1.x; q1p[1] = s1a1.y; q1p[2] = s1b1.x; q1p[3] = s1b1.y;
    q1p[4] = s2a1.x; q1p[5] = s2a1.y; q1p[6] = s2b1.x; q1p[7] = s2b1.y;
  }
  __syncthreads();
  if (t < 256) {                            // reduce q0
    const int hd = t, h = hd >> 5, d = hd & 31, dg = d >> 2, c = d & 3;
    float S1 = 0.f, S2 = 0.f;
    #pragma unroll
    for (int s = 0; s < 8; ++s) {
      const float* row = s_redA + (size_t)(s * 64 + h * 8 + dg) * 9;
      S1 += row[c]; S2 += row[4 + c];
    }
    float inv = 1.0f / s_sum[0][h];
    float m1 = S1 * inv;
    float va = fmaxf(S2 * inv - m1 * m1, 0.f);
    s_hv[0 * 256 + hd] = m1;
    s_hv[1 * 256 + hd] = va;
  }
  __syncthreads();
  {
    float* row = s_redA + t * 9;
    #pragma unroll
    for (int i = 0; i < 8; ++i) row[i] = q1p[i];
  }
  __syncthreads();
  if (t < 256) {                            // reduce q1
    const int hd = t, h = hd >> 5, d = hd & 31, dg = d >> 2, c = d & 3;
    float S1 = 0.f, S2 = 0.f;
    #pragma unroll
    for (int s = 0; s < 8; ++s) {
      const float* row = s_redA + (size_t)(s * 64 + h * 8 + dg) * 9;
      S1 += row[c]; S2 += row[4 + c];
    }
    float inv = 1.0f / s_sum[1][h];
    float m1 = S1 * inv;
    float va = fmaxf(S2 * inv - m1 * m1, 0.f);
    s_hv[2 * 256 + hd] = m1;
    s_hv[3 * 256 + hd] = va;
  }
  __syncthreads();

  // ---- phase 4: out_proj, k-split 2, W read once per (mode,ks) ------------
  {
    const int ks = t >> 8, mode = (t >> 7) & 1, n = t & 127;
    const float* W  = mode ? vw : ow;
    const float* X0 = s_hv + mode * 256;        // q0
    const float* X1 = s_hv + (2 + mode) * 256;  // q1
    float a0 = 0.f, a1 = 0.f;
    const int k0 = ks * 128;
    #pragma unroll 4
    for (int k = k0; k < k0 + 128; k += 4) {
      float4 x0 = *(const float4*)&X0[k];
      float4 x1 = *(const float4*)&X1[k];
      float w0 = W[(k + 0) * 128 + n];
      float w1 = W[(k + 1) * 128 + n];
      float w2 = W[(k + 2) * 128 + n];
      float w3 = W[(k + 3) * 128 + n];
      a0 = fmaf(x0.x, w0, a0); a1 = fmaf(x1.x, w0, a1);
      a0 = fmaf(x0.y, w1, a0); a1 = fmaf(x1.y, w1, a1);
      a0 = fmaf(x0.z, w2, a0); a1 = fmaf(x1.z, w2, a1);
      a0 = fmaf(x0.w, w3, a0); a1 = fmaf(x1.w, w3, a1);
    }
    __syncthreads();                            // s_redA dead; reuse as s_pred
    s_pred[((ks * 2 + mode) * 2 + 0) * 128 + n] = a0;
    s_pred[((ks * 2 + mode) * 2 + 1) * 128 + n] = a1;
  }
  __syncthreads();
  {
    const int q = t >> 8, mode = (t >> 7) & 1, n = t & 127;
    float v = s_pred[((0 * 2 + mode) * 2 + q) * 128 + n]
            + s_pred[((1 * 2 + mode) * 2 + q) * 128 + n]
            + (mode ? vbias[n] : obias[n]);
    if (mode) v = softplus_f(v);
    out[(size_t)mode * (NB * NQ * OUT_DIM) + (size_t)(bq0 + q) * OUT_DIM + n] = v;
  }
}

// ---------------------------------------------------------------------------
extern "C" void kernel_launch(void* const* d_in, const int* in_sizes, int n_in,
                              void* d_out, int out_size, void* d_ws, size_t ws_size,
                              hipStream_t stream)
{
  const float* h_obs     = (const float*)d_in[0];
  const float* pos_obs   = (const float*)d_in[1];
  const float* pos_query = (const float*)d_in[2];
  const float* fw1       = (const float*)d_in[3];
  const float* fb1       = (const float*)d_in[4];
  const float* fw2       = (const float*)d_in[5];
  const float* fb2       = (const float*)d_in[6];
  const float* log_sigma = (const float*)d_in[7];
  const float* kw1       = (const float*)d_in[8];
  const float* kb1       = (const float*)d_in[9];
  const float* kw2       = (const float*)d_in[10];
  const float* kb2       = (const float*)d_in[11];
  const float* ow        = (const float*)d_in[12];
  const float* ob        = (const float*)d_in[13];
  const float* vw        = (const float*)d_in[14];
  const float* vb        = (const float*)d_in[15];

  float* out = (float*)d_out;
  unsigned short* ws = (unsigned short*)d_ws;

  unsigned short* V_bf  = ws;            // 262144 ushort = 512 KB
  unsigned short* AO_bf = ws + 262144;   // 262144 ushort

  prep_kernel<<<512, 1024, 0, stream>>>(h_obs, fw1, fb1, fw2, fb2,
                                        pos_obs, kw1, V_bf, AO_bf);
  attn_fused<<<NB * NQ / 2, 512, 0, stream>>>(V_bf, AO_bf, kw1, kb1, kw2, kb2,
                                              log_sigma, pos_obs, pos_query,
                                              ow, ob, vw, vb, out);
}